// Round 1
// baseline (1096.722 us; speedup 1.0000x reference)
//
#include <hip/hip_runtime.h>
#include <math.h>

#define BATCH 64
#define CIN   256
#define HH    56
#define WW    56
#define HW    (HH*WW)      // 3136
#define WIDTH 64
#define COUT  256
#define K_CH  32
#define K_SP  1568
#define EPS   1e-5f

// ---------------- Kernel 1: global average pool (double) ----------------
// grid = BATCH*CIN blocks, 256 threads
__global__ __launch_bounds__(256) void k_pool(const float* __restrict__ x, double* __restrict__ pooled) {
    int bc = blockIdx.x;
    const float* px = x + (size_t)bc * HW;
    double s = 0.0;
    for (int i = threadIdx.x; i < HW; i += 256) s += (double)px[i];
    __shared__ double red[256];
    red[threadIdx.x] = s;
    __syncthreads();
    for (int off = 128; off > 0; off >>= 1) {
        if (threadIdx.x < off) red[threadIdx.x] += red[threadIdx.x + off];
        __syncthreads();
    }
    if (threadIdx.x == 0) pooled[bc] = red[0] * (1.0 / (double)HW);
}

// ---------------- Kernel 2: spatial saliency 1x1 conv (double accum) ----------------
// grid = B*HW/256 = 784 blocks, 256 threads
__global__ __launch_bounds__(256) void k_spsal(const float* __restrict__ x,
                                               const float* __restrict__ mask_w,
                                               const float* __restrict__ mask_b,
                                               double* __restrict__ spsal) {
    __shared__ float wsh[CIN];
    for (int i = threadIdx.x; i < CIN; i += 256) wsh[i] = mask_w[i];
    __syncthreads();
    int g = blockIdx.x * 256 + threadIdx.x;
    if (g >= BATCH * HW) return;
    int b = g / HW, p = g % HW;
    const float* px = x + (size_t)b * CIN * HW + p;
    double acc = 0.0;
#pragma unroll 8
    for (int c = 0; c < CIN; c++) acc += (double)px[(size_t)c * HW] * (double)wsh[c];
    spsal[g] = acc + (double)mask_b[0];
}

// ---------------- Kernel 3: channel saliency + top-K_CH mask ----------------
// grid = BATCH blocks, 64 threads
__global__ __launch_bounds__(64) void k_chan(const double* __restrict__ pooled,
                                             const float* __restrict__ fc_w,
                                             const float* __restrict__ fc_b,
                                             float* __restrict__ vector) {
    int b = blockIdx.x;
    int j = threadIdx.x;
    __shared__ double ps[CIN];
    for (int i = j; i < CIN; i += 64) ps[i] = pooled[b * CIN + i];
    __syncthreads();
    double acc = (double)fc_b[j];
    const float* wr = fc_w + j * CIN;
    for (int k = 0; k < CIN; k++) acc += ps[k] * (double)wr[k];
    double sal = 1.0 / (1.0 + exp(-acc));
    __shared__ double ss[WIDTH];
    __shared__ double kth;
    ss[j] = sal;
    __syncthreads();
    int cg = 0, ce = 0;
    for (int i = 0; i < WIDTH; i++) {
        cg += (ss[i] > sal);
        ce += (ss[i] == sal);
    }
    if (cg <= K_CH - 1 && cg + ce >= K_CH) kth = sal;  // unique value; ties write same
    __syncthreads();
    vector[b * WIDTH + j] = (sal >= kth) ? 1.0f : 0.0f;
}

// ---------------- Kernel 4: spatial kth (bitonic select) + mask + 3x3 dilate ----------------
// grid = BATCH blocks, 1024 threads
__global__ __launch_bounds__(1024) void k_spmask(const double* __restrict__ spsal,
                                                 float* __restrict__ mask,
                                                 float* __restrict__ mdil) {
    int b = blockIdx.x;
    int tid = threadIdx.x;
    __shared__ double s[4096];
    __shared__ float m[HW];
    for (int i = tid; i < 4096; i += 1024)
        s[i] = (i < HW) ? spsal[b * HW + i] : 1e300;
    __syncthreads();
    // bitonic sort ascending; pads (+huge) land at the top
    for (int k2 = 2; k2 <= 4096; k2 <<= 1) {
        for (int j2 = k2 >> 1; j2 > 0; j2 >>= 1) {
            for (int i = tid; i < 4096; i += 1024) {
                int ixj = i ^ j2;
                if (ixj > i) {
                    double a = s[i], c = s[ixj];
                    bool asc = ((i & k2) == 0);
                    bool swap = asc ? (a > c) : (a < c);
                    if (swap) { s[i] = c; s[ixj] = a; }
                }
            }
            __syncthreads();
        }
    }
    double kth = s[HW - K_SP];  // = value at descending index K_SP-1
    __syncthreads();
    for (int p = tid; p < HW; p += 1024) {
        float mv = (spsal[b * HW + p] >= kth) ? 1.0f : 0.0f;
        m[p] = mv;
        mask[b * HW + p] = mv;
    }
    __syncthreads();
    for (int p = tid; p < HW; p += 1024) {
        int y = p / WW, xx = p % WW;
        float mx = 0.0f;
        for (int dy = -1; dy <= 1; dy++) {
            int yy = y + dy;
            if (yy < 0 || yy >= HH) continue;
            for (int dx = -1; dx <= 1; dx++) {
                int xc = xx + dx;
                if (xc < 0 || xc >= WW) continue;
                mx = fmaxf(mx, m[yy * WW + xc]);
            }
        }
        mdil[b * HW + p] = mx;
    }
}

// ---------------- Kernel 5: conv1 1x1 (256->64) + bn1 + relu + mask_dilate + vector ----------------
// grid = (13, BATCH), 256 threads; thread = 1 pixel, 64 output channels
__global__ __launch_bounds__(256) void k_conv1(const float* __restrict__ x,
                                               const float* __restrict__ w1,
                                               const float* __restrict__ g1, const float* __restrict__ b1,
                                               const float* __restrict__ m1, const float* __restrict__ v1,
                                               const float* __restrict__ mdil,
                                               const float* __restrict__ vector,
                                               float* __restrict__ out1) {
    int b = blockIdx.y;
    int p = blockIdx.x * 256 + threadIdx.x;
    bool valid = p < HW;
    __shared__ float wl[64][64];
    __shared__ float sc[WIDTH], sh[WIDTH], vecs[WIDTH];
    if (threadIdx.x < WIDTH) {
        int j = threadIdx.x;
        float s = g1[j] / sqrtf(v1[j] + EPS);
        sc[j] = s;
        sh[j] = b1[j] - m1[j] * s;
        vecs[j] = vector[b * WIDTH + j];
    }
    float acc[64];
#pragma unroll
    for (int j = 0; j < 64; j++) acc[j] = 0.0f;

    for (int cc = 0; cc < CIN; cc += 64) {
        __syncthreads();
        for (int i = threadIdx.x; i < 4096; i += 256) {
            int j = i >> 6, ci = i & 63;
            wl[j][ci] = w1[j * CIN + cc + ci];
        }
        __syncthreads();
        for (int ci = 0; ci < 64; ci++) {
            float xv = valid ? x[(size_t)(b * CIN + cc + ci) * HW + p] : 0.0f;
#pragma unroll
            for (int j = 0; j < 64; j++) acc[j] += xv * wl[j][ci];
        }
    }
    if (valid) {
        float md = mdil[b * HW + p];
#pragma unroll
        for (int j = 0; j < 64; j++) {
            float y = acc[j] * sc[j] + sh[j];
            y = fmaxf(y, 0.0f) * md * vecs[j];
            out1[(size_t)(b * WIDTH + j) * HW + p] = y;
        }
    }
}

// ---------------- Kernel 6: conv2 3x3 (64->64, pad 1) + bn2 + relu + mask + vector ----------------
// grid = (7, BATCH), 448 threads (56x8 tile); thread = 1 pixel, 64 output channels
__global__ __launch_bounds__(448) void k_conv2(const float* __restrict__ out1,
                                               const float* __restrict__ w2,
                                               const float* __restrict__ g2, const float* __restrict__ b2,
                                               const float* __restrict__ m2, const float* __restrict__ v2,
                                               const float* __restrict__ mask,
                                               const float* __restrict__ vector,
                                               float* __restrict__ out2) {
    int b = blockIdx.y;
    int tile = blockIdx.x;  // 8-row tile
    int tid = threadIdx.x;
    int r = tid / WW;       // 0..7
    int xx = tid % WW;      // 0..55
    __shared__ float sin_t[10 * WW];
    __shared__ float wl[64 * 9];
    __shared__ float sc[64], sh[64], vecs[64];
    if (tid < 64) {
        float s = g2[tid] / sqrtf(v2[tid] + EPS);
        sc[tid] = s;
        sh[tid] = b2[tid] - m2[tid] * s;
        vecs[tid] = vector[b * 64 + tid];
    }
    float acc[64];
#pragma unroll
    for (int j = 0; j < 64; j++) acc[j] = 0.0f;

    for (int c = 0; c < 64; c++) {
        __syncthreads();
        for (int i = tid; i < 10 * WW; i += 448) {
            int ry = i / WW, rx = i % WW;
            int gy = tile * 8 + ry - 1;
            sin_t[i] = (gy >= 0 && gy < HH) ? out1[(size_t)(b * 64 + c) * HW + gy * WW + rx] : 0.0f;
        }
        for (int i = tid; i < 576; i += 448) {
            int j = i / 9, t = i % 9;
            wl[i] = w2[j * (64 * 9) + c * 9 + t];
        }
        __syncthreads();
        float n[9];
#pragma unroll
        for (int dy = 0; dy < 3; dy++) {
#pragma unroll
            for (int dx = 0; dx < 3; dx++) {
                int xc = xx + dx - 1;
                n[dy * 3 + dx] = (xc >= 0 && xc < WW) ? sin_t[(r + dy) * WW + xc] : 0.0f;
            }
        }
#pragma unroll
        for (int j = 0; j < 64; j++) {
            const float* wj = &wl[j * 9];
            acc[j] += n[0]*wj[0] + n[1]*wj[1] + n[2]*wj[2]
                    + n[3]*wj[3] + n[4]*wj[4] + n[5]*wj[5]
                    + n[6]*wj[6] + n[7]*wj[7] + n[8]*wj[8];
        }
    }
    int gy = tile * 8 + r;
    int p = gy * WW + xx;
    float mv = mask[b * HW + p];
#pragma unroll
    for (int j = 0; j < 64; j++) {
        float y = fmaxf(acc[j] * sc[j] + sh[j], 0.0f) * mv * vecs[j];
        out2[(size_t)(b * 64 + j) * HW + p] = y;
    }
}

// ---------------- Kernel 7: conv3 1x1 (64->256) + bn3 + mask + residual + relu ----------------
// grid = (13, BATCH), 256 threads; thread = 1 pixel, 256 output channels in 4 chunks
__global__ __launch_bounds__(256) void k_conv3(const float* __restrict__ out2,
                                               const float* __restrict__ w3,
                                               const float* __restrict__ g3, const float* __restrict__ b3,
                                               const float* __restrict__ m3, const float* __restrict__ v3,
                                               const float* __restrict__ mask,
                                               const float* __restrict__ x,
                                               float* __restrict__ out) {
    int b = blockIdx.y;
    int p = blockIdx.x * 256 + threadIdx.x;
    bool valid = p < HW;
    __shared__ float sc[COUT], sh[COUT];
    {
        int o = threadIdx.x;
        float s = g3[o] / sqrtf(v3[o] + EPS);
        sc[o] = s;
        sh[o] = b3[o] - m3[o] * s;
    }
    __shared__ float wl[64][64];
    float v[64];
    if (valid) {
#pragma unroll
        for (int c = 0; c < 64; c++) v[c] = out2[(size_t)(b * 64 + c) * HW + p];
    } else {
#pragma unroll
        for (int c = 0; c < 64; c++) v[c] = 0.0f;
    }
    float mv = valid ? mask[b * HW + p] : 0.0f;

    for (int oc = 0; oc < 4; oc++) {
        __syncthreads();
        for (int i = threadIdx.x; i < 4096; i += 256) {
            int o = i >> 6, c = i & 63;
            wl[o][c] = w3[(oc * 64 + o) * 64 + c];
        }
        __syncthreads();
        for (int o = 0; o < 64; o += 4) {
            float a0 = 0, a1 = 0, a2 = 0, a3 = 0;
#pragma unroll
            for (int c = 0; c < 64; c++) {
                float vc = v[c];
                a0 += vc * wl[o + 0][c];
                a1 += vc * wl[o + 1][c];
                a2 += vc * wl[o + 2][c];
                a3 += vc * wl[o + 3][c];
            }
            if (valid) {
                int o0 = oc * 64 + o;
                float y0 = (a0 * sc[o0 + 0] + sh[o0 + 0]) * mv;
                float y1 = (a1 * sc[o0 + 1] + sh[o0 + 1]) * mv;
                float y2 = (a2 * sc[o0 + 2] + sh[o0 + 2]) * mv;
                float y3 = (a3 * sc[o0 + 3] + sh[o0 + 3]) * mv;
                out[(size_t)(b * COUT + o0 + 0) * HW + p] = fmaxf(x[(size_t)(b * COUT + o0 + 0) * HW + p] + y0, 0.0f);
                out[(size_t)(b * COUT + o0 + 1) * HW + p] = fmaxf(x[(size_t)(b * COUT + o0 + 1) * HW + p] + y1, 0.0f);
                out[(size_t)(b * COUT + o0 + 2) * HW + p] = fmaxf(x[(size_t)(b * COUT + o0 + 2) * HW + p] + y2, 0.0f);
                out[(size_t)(b * COUT + o0 + 3) * HW + p] = fmaxf(x[(size_t)(b * COUT + o0 + 3) * HW + p] + y3, 0.0f);
            }
        }
    }
}

extern "C" void kernel_launch(void* const* d_in, const int* in_sizes, int n_in,
                              void* d_out, int out_size, void* d_ws, size_t ws_size,
                              hipStream_t stream) {
    const float* x       = (const float*)d_in[0];
    const float* conv1_w = (const float*)d_in[1];
    const float* bn1_g   = (const float*)d_in[2];
    const float* bn1_b   = (const float*)d_in[3];
    const float* bn1_m   = (const float*)d_in[4];
    const float* bn1_v   = (const float*)d_in[5];
    const float* conv2_w = (const float*)d_in[6];
    const float* bn2_g   = (const float*)d_in[7];
    const float* bn2_b   = (const float*)d_in[8];
    const float* bn2_m   = (const float*)d_in[9];
    const float* bn2_v   = (const float*)d_in[10];
    const float* conv3_w = (const float*)d_in[11];
    const float* bn3_g   = (const float*)d_in[12];
    const float* bn3_b   = (const float*)d_in[13];
    const float* bn3_m   = (const float*)d_in[14];
    const float* bn3_v   = (const float*)d_in[15];
    const float* fc_w    = (const float*)d_in[16];
    const float* fc_b    = (const float*)d_in[17];
    const float* mask_w  = (const float*)d_in[18];
    const float* mask_b  = (const float*)d_in[19];

    char* wsb = (char*)d_ws;
    size_t off = 0;
    double* pooled = (double*)(wsb + off); off += (size_t)BATCH * CIN * 8;
    double* spsal  = (double*)(wsb + off); off += (size_t)BATCH * HW * 8;
    float* vector  = (float*)(wsb + off);  off += (size_t)BATCH * WIDTH * 4;
    float* mask    = (float*)(wsb + off);  off += (size_t)BATCH * HW * 4;
    float* mdil    = (float*)(wsb + off);  off += (size_t)BATCH * HW * 4;
    float* out1    = (float*)(wsb + off);  off += (size_t)BATCH * WIDTH * HW * 4;
    float* out2    = (float*)(wsb + off);  off += (size_t)BATCH * WIDTH * HW * 4;
    (void)ws_size; (void)in_sizes; (void)n_in; (void)out_size;

    k_pool<<<BATCH * CIN, 256, 0, stream>>>(x, pooled);
    k_spsal<<<(BATCH * HW + 255) / 256, 256, 0, stream>>>(x, mask_w, mask_b, spsal);
    k_chan<<<BATCH, 64, 0, stream>>>(pooled, fc_w, fc_b, vector);
    k_spmask<<<BATCH, 1024, 0, stream>>>(spsal, mask, mdil);
    k_conv1<<<dim3(13, BATCH), 256, 0, stream>>>(x, conv1_w, bn1_g, bn1_b, bn1_m, bn1_v, mdil, vector, out1);
    k_conv2<<<dim3(7, BATCH), 448, 0, stream>>>(out1, conv2_w, bn2_g, bn2_b, bn2_m, bn2_v, mask, vector, out2);
    k_conv3<<<dim3(13, BATCH), 256, 0, stream>>>(out2, conv3_w, bn3_g, bn3_b, bn3_m, bn3_v, mask, x, (float*)d_out);
}

// Round 2
// 533.707 us; speedup vs baseline: 2.0549x; 2.0549x over previous
//
#include <hip/hip_runtime.h>
#include <math.h>

#define BATCH 64
#define CIN   256
#define HH    56
#define WW    56
#define HW    (HH*WW)      // 3136
#define WIDTH 64
#define COUT  256
#define K_CH  32
#define K_SP  1568
#define EPS   1e-5f

typedef short short8 __attribute__((ext_vector_type(8)));
typedef float f32x4 __attribute__((ext_vector_type(4)));

#define MFMA16(a, b, c) __builtin_amdgcn_mfma_f32_16x16x32_bf16((a), (b), (c), 0, 0, 0)

__device__ __forceinline__ unsigned short f2bf(float f) {
    unsigned u = __builtin_bit_cast(unsigned, f);
    u += 0x7fffu + ((u >> 16) & 1u);
    return (unsigned short)(u >> 16);
}

// ---------------- Kernel 0: weight prep (fp32 -> bf16, conv2 -> [tap][oc][c]) ----------------
__global__ __launch_bounds__(256) void k_prep(const float* __restrict__ w1,
                                              const float* __restrict__ w2,
                                              const float* __restrict__ w3,
                                              short* __restrict__ w1bf,
                                              short* __restrict__ wt2,
                                              short* __restrict__ w3bf) {
    int i = blockIdx.x * 256 + threadIdx.x;
    if (i < 16384) {
        w1bf[i] = (short)f2bf(w1[i]);
    } else if (i < 53248) {
        int j = i - 16384;              // [tap][oc][c]
        int tap = j >> 12, rem = j & 4095;
        int oc = rem >> 6, c = rem & 63;
        wt2[j] = (short)f2bf(w2[oc * 576 + c * 9 + tap]);
    } else if (i < 69632) {
        int j = i - 53248;
        w3bf[j] = (short)f2bf(w3[j]);
    }
}

// ---------------- Kernel 1: global average pool (double) ----------------
__global__ __launch_bounds__(256) void k_pool(const float* __restrict__ x, double* __restrict__ pooled) {
    int bc = blockIdx.x;
    const float* px = x + (size_t)bc * HW;
    double s = 0.0;
    for (int i = threadIdx.x; i < HW; i += 256) s += (double)px[i];
    __shared__ double red[256];
    red[threadIdx.x] = s;
    __syncthreads();
    for (int off = 128; off > 0; off >>= 1) {
        if (threadIdx.x < off) red[threadIdx.x] += red[threadIdx.x + off];
        __syncthreads();
    }
    if (threadIdx.x == 0) pooled[bc] = red[0] * (1.0 / (double)HW);
}

// ---------------- Kernel 2: spatial saliency 1x1 conv (double accum) ----------------
__global__ __launch_bounds__(256) void k_spsal(const float* __restrict__ x,
                                               const float* __restrict__ mask_w,
                                               const float* __restrict__ mask_b,
                                               double* __restrict__ spsal) {
    __shared__ float wsh[CIN];
    for (int i = threadIdx.x; i < CIN; i += 256) wsh[i] = mask_w[i];
    __syncthreads();
    int g = blockIdx.x * 256 + threadIdx.x;
    if (g >= BATCH * HW) return;
    int b = g / HW, p = g % HW;
    const float* px = x + (size_t)b * CIN * HW + p;
    double acc = 0.0;
#pragma unroll 8
    for (int c = 0; c < CIN; c++) acc += (double)px[(size_t)c * HW] * (double)wsh[c];
    spsal[g] = acc + (double)mask_b[0];
}

// ---------------- Kernel 3: channel saliency + top-K_CH mask ----------------
__global__ __launch_bounds__(64) void k_chan(const double* __restrict__ pooled,
                                             const float* __restrict__ fc_w,
                                             const float* __restrict__ fc_b,
                                             float* __restrict__ vector) {
    int b = blockIdx.x;
    int j = threadIdx.x;
    __shared__ double ps[CIN];
    for (int i = j; i < CIN; i += 64) ps[i] = pooled[b * CIN + i];
    __syncthreads();
    double acc = (double)fc_b[j];
    const float* wr = fc_w + j * CIN;
    for (int k = 0; k < CIN; k++) acc += ps[k] * (double)wr[k];
    double sal = 1.0 / (1.0 + exp(-acc));
    __shared__ double ss[WIDTH];
    __shared__ double kth;
    ss[j] = sal;
    __syncthreads();
    int cg = 0, ce = 0;
    for (int i = 0; i < WIDTH; i++) {
        cg += (ss[i] > sal);
        ce += (ss[i] == sal);
    }
    if (cg <= K_CH - 1 && cg + ce >= K_CH) kth = sal;
    __syncthreads();
    vector[b * WIDTH + j] = (sal >= kth) ? 1.0f : 0.0f;
}

// ---------------- Kernel 4: spatial kth (bitonic select) + mask + 3x3 dilate ----------------
__global__ __launch_bounds__(1024) void k_spmask(const double* __restrict__ spsal,
                                                 float* __restrict__ mask,
                                                 float* __restrict__ mdil) {
    int b = blockIdx.x;
    int tid = threadIdx.x;
    __shared__ double s[4096];
    __shared__ float m[HW];
    for (int i = tid; i < 4096; i += 1024)
        s[i] = (i < HW) ? spsal[b * HW + i] : 1e300;
    __syncthreads();
    for (int k2 = 2; k2 <= 4096; k2 <<= 1) {
        for (int j2 = k2 >> 1; j2 > 0; j2 >>= 1) {
            for (int i = tid; i < 4096; i += 1024) {
                int ixj = i ^ j2;
                if (ixj > i) {
                    double a = s[i], c = s[ixj];
                    bool asc = ((i & k2) == 0);
                    bool swap = asc ? (a > c) : (a < c);
                    if (swap) { s[i] = c; s[ixj] = a; }
                }
            }
            __syncthreads();
        }
    }
    double kth = s[HW - K_SP];
    __syncthreads();
    for (int p = tid; p < HW; p += 1024) {
        float mv = (spsal[b * HW + p] >= kth) ? 1.0f : 0.0f;
        m[p] = mv;
        mask[b * HW + p] = mv;
    }
    __syncthreads();
    for (int p = tid; p < HW; p += 1024) {
        int y = p / WW, xx = p % WW;
        float mx = 0.0f;
        for (int dy = -1; dy <= 1; dy++) {
            int yy = y + dy;
            if (yy < 0 || yy >= HH) continue;
            for (int dx = -1; dx <= 1; dx++) {
                int xc = xx + dx;
                if (xc < 0 || xc >= WW) continue;
                mx = fmaxf(mx, m[yy * WW + xc]);
            }
        }
        mdil[b * HW + p] = mx;
    }
}

// ---------------- Kernel 5: conv1 1x1 (256->64) MFMA + bn1 + relu + mdil + vector -> NHWC bf16 ----------------
// grid (7, BATCH), 256 thr = 4 waves. Block: 8 rows (448 px), all 64 oc.
// Wave w: n-tiles w*7..w*7+6 (7 tiles of 16 px), 4 m-tiles of 16 oc. acc = 4x7 f32x4.
__global__ __launch_bounds__(256, 2) void k_conv1(const float* __restrict__ x,
                                                  const short* __restrict__ w1bf,
                                                  const float* __restrict__ g1, const float* __restrict__ b1,
                                                  const float* __restrict__ m1, const float* __restrict__ v1,
                                                  const float* __restrict__ mdil,
                                                  const float* __restrict__ vec,
                                                  short* __restrict__ out1h) {
    __shared__ short lds[448 * 64];   // [px][c^swz], 57344 B
    __shared__ float sc[64], sh[64], vs[64];
    int b = blockIdx.y, r0 = blockIdx.x * 8, p0 = r0 * 56;
    int tid = threadIdx.x, w = tid >> 6, lane = tid & 63, g = lane >> 4, ln = lane & 15;
    if (tid < 64) {
        float s = g1[tid] * rsqrtf(v1[tid] + EPS);
        sc[tid] = s; sh[tid] = b1[tid] - m1[tid] * s;
        vs[tid] = vec[b * 64 + tid];
    }
    f32x4 acc[4][7];
    f32x4 zz = {0.f, 0.f, 0.f, 0.f};
#pragma unroll
    for (int m = 0; m < 4; m++)
#pragma unroll
        for (int nt = 0; nt < 7; nt++) acc[m][nt] = zz;

    int pxl0 = w * 112 + ln;                 // block-relative pixel at nt=0
    int swl = (pxl0 & 7) << 3;               // nt adds 16 -> invariant

    for (int kc = 0; kc < 4; kc++) {
        __syncthreads();
        const float* xsrc = x + ((size_t)(b * 256 + kc * 64)) * HW + p0;
        {
            int c = 0, px = tid;
            for (int i = 0; i < 112; i++) {
                float f = xsrc[(size_t)c * HW + px];
                lds[px * 64 + (c ^ ((px & 7) << 3))] = (short)f2bf(f);
                px += 256;
                if (px >= 448) { px -= 448; c++; }
            }
        }
        __syncthreads();
        short8 afr[4][2];
#pragma unroll
        for (int m = 0; m < 4; m++)
#pragma unroll
            for (int ks = 0; ks < 2; ks++)
                afr[m][ks] = *(const short8*)(w1bf + ((m * 16 + ln) * 256 + kc * 64 + ks * 32 + g * 8));
#pragma unroll
        for (int nt = 0; nt < 7; nt++) {
#pragma unroll
            for (int ks = 0; ks < 2; ks++) {
                short8 bfr = *(const short8*)(&lds[(pxl0 + nt * 16) * 64 + (((ks * 32 + g * 8)) ^ swl)]);
#pragma unroll
                for (int m = 0; m < 4; m++) acc[m][nt] = MFMA16(afr[m][ks], bfr, acc[m][nt]);
            }
        }
    }
    // epilogue
#pragma unroll
    for (int nt = 0; nt < 7; nt++) {
        int px = p0 + pxl0 + nt * 16;
        float md = mdil[b * HW + px];
#pragma unroll
        for (int m = 0; m < 4; m++) {
            unsigned pk0, pk1;
            {
                int oc = m * 16 + g * 4;
                float y0 = fmaxf(acc[m][nt][0] * sc[oc + 0] + sh[oc + 0], 0.f) * md * vs[oc + 0];
                float y1 = fmaxf(acc[m][nt][1] * sc[oc + 1] + sh[oc + 1], 0.f) * md * vs[oc + 1];
                float y2 = fmaxf(acc[m][nt][2] * sc[oc + 2] + sh[oc + 2], 0.f) * md * vs[oc + 2];
                float y3 = fmaxf(acc[m][nt][3] * sc[oc + 3] + sh[oc + 3], 0.f) * md * vs[oc + 3];
                pk0 = (unsigned)f2bf(y0) | ((unsigned)f2bf(y1) << 16);
                pk1 = (unsigned)f2bf(y2) | ((unsigned)f2bf(y3) << 16);
            }
            uint2 u; u.x = pk0; u.y = pk1;
            *(uint2*)(out1h + ((size_t)(b * HW + px)) * 64 + m * 16 + g * 4) = u;
        }
    }
}

// ---------------- Kernel 6: conv2 3x3 (64->64) MFMA shift-GEMM + bn2 + relu + mask + vector ----------------
// grid (7, BATCH), 256 thr. LDS: halo tile [10 rows][58 cols][64 c] bf16, col-swizzled.
__global__ __launch_bounds__(256, 2) void k_conv2(const short* __restrict__ out1h,
                                                  const short* __restrict__ wt2,
                                                  const float* __restrict__ g2, const float* __restrict__ b2,
                                                  const float* __restrict__ m2, const float* __restrict__ v2,
                                                  const float* __restrict__ mask,
                                                  const float* __restrict__ vec,
                                                  short* __restrict__ out2h) {
    __shared__ short lds[10 * 58 * 64];   // 74240 B
    __shared__ float sc[64], sh[64], vs[64];
    int b = blockIdx.y, r0 = blockIdx.x * 8, p0 = r0 * 56;
    int tid = threadIdx.x, w = tid >> 6, lane = tid & 63, g = lane >> 4, ln = lane & 15;
    if (tid < 64) {
        float s = g2[tid] * rsqrtf(v2[tid] + EPS);
        sc[tid] = s; sh[tid] = b2[tid] - m2[tid] * s;
        vs[tid] = vec[b * 64 + tid];
    }
    // stage halo tile (zero-padded), vectorized 8-ch chunks, coalesced NHWC reads
    short8 z8 = {0, 0, 0, 0, 0, 0, 0, 0};
    for (int i = tid; i < 4640; i += 256) {       // 10*58*8 chunks
        int ri = i / 464, rem = i - ri * 464;
        int col = rem >> 3, c8 = (rem & 7) << 3;
        int gr = r0 - 1 + ri, gc = col - 1;
        short8 v8 = z8;
        if (gr >= 0 && gr < HH && gc >= 0 && gc < WW)
            v8 = *(const short8*)(out1h + ((size_t)(b * HW + gr * WW + gc)) * 64 + c8);
        *(short8*)(&lds[(ri * 58 + col) * 64 + (c8 ^ ((col & 7) << 3))]) = v8;
    }
    __syncthreads();

    f32x4 acc[4][7];
    f32x4 zz = {0.f, 0.f, 0.f, 0.f};
#pragma unroll
    for (int m = 0; m < 4; m++)
#pragma unroll
        for (int nt = 0; nt < 7; nt++) acc[m][nt] = zz;

    int prel0 = w * 112 + ln;
    for (int tap = 0; tap < 9; tap++) {
        int dy = tap / 3 - 1;
        int dx = tap - (tap / 3) * 3 - 1;
        short8 afr[4][2];
        const short* wt = wt2 + tap * 4096;
#pragma unroll
        for (int m = 0; m < 4; m++)
#pragma unroll
            for (int ks = 0; ks < 2; ks++)
                afr[m][ks] = *(const short8*)(wt + (m * 16 + ln) * 64 + ks * 32 + g * 8);
#pragma unroll
        for (int nt = 0; nt < 7; nt++) {
            int prel = prel0 + nt * 16;
            int rrel = prel / 56;
            int xcol = prel - rrel * 56;
            int row_l = rrel + 1 + dy;       // 0..9
            int col_l = xcol + 1 + dx;       // 0..57
            int base = (row_l * 58 + col_l) * 64;
            int sw = (col_l & 7) << 3;
#pragma unroll
            for (int ks = 0; ks < 2; ks++) {
                short8 bfr = *(const short8*)(&lds[base + ((ks * 32 + g * 8) ^ sw)]);
#pragma unroll
                for (int m = 0; m < 4; m++) acc[m][nt] = MFMA16(afr[m][ks], bfr, acc[m][nt]);
            }
        }
    }
    // epilogue
#pragma unroll
    for (int nt = 0; nt < 7; nt++) {
        int px = p0 + prel0 + nt * 16;
        float mv = mask[b * HW + px];
#pragma unroll
        for (int m = 0; m < 4; m++) {
            int oc = m * 16 + g * 4;
            float y0 = fmaxf(acc[m][nt][0] * sc[oc + 0] + sh[oc + 0], 0.f) * mv * vs[oc + 0];
            float y1 = fmaxf(acc[m][nt][1] * sc[oc + 1] + sh[oc + 1], 0.f) * mv * vs[oc + 1];
            float y2 = fmaxf(acc[m][nt][2] * sc[oc + 2] + sh[oc + 2], 0.f) * mv * vs[oc + 2];
            float y3 = fmaxf(acc[m][nt][3] * sc[oc + 3] + sh[oc + 3], 0.f) * mv * vs[oc + 3];
            uint2 u;
            u.x = (unsigned)f2bf(y0) | ((unsigned)f2bf(y1) << 16);
            u.y = (unsigned)f2bf(y2) | ((unsigned)f2bf(y3) << 16);
            *(uint2*)(out2h + ((size_t)(b * HW + px)) * 64 + m * 16 + g * 4) = u;
        }
    }
}

// ---------------- Kernel 7: conv3 1x1 (64->256) MFMA + bn3 + mask + residual + relu -> fp32 NCHW ----------------
// grid (28, BATCH), 256 thr = 4 waves; wave w: oc w*64..w*64+63 (4 m-tiles), 7 n-tiles of 16 px.
__global__ __launch_bounds__(256, 2) void k_conv3(const short* __restrict__ out2h,
                                                  const short* __restrict__ w3bf,
                                                  const float* __restrict__ g3, const float* __restrict__ b3,
                                                  const float* __restrict__ m3, const float* __restrict__ v3,
                                                  const float* __restrict__ mask,
                                                  const float* __restrict__ x,
                                                  float* __restrict__ out) {
    __shared__ float sc[COUT], sh[COUT];
    int b = blockIdx.y, p0 = blockIdx.x * 112;
    int tid = threadIdx.x, w = tid >> 6, lane = tid & 63, g = lane >> 4, ln = lane & 15;
    {
        float s = g3[tid] * rsqrtf(v3[tid] + EPS);
        sc[tid] = s; sh[tid] = b3[tid] - m3[tid] * s;
    }
    __syncthreads();
    short8 afr[4][2];
#pragma unroll
    for (int m = 0; m < 4; m++)
#pragma unroll
        for (int ks = 0; ks < 2; ks++)
            afr[m][ks] = *(const short8*)(w3bf + ((w * 64 + m * 16 + ln) * 64 + ks * 32 + g * 8));
    f32x4 acc[4][7];
    f32x4 zz = {0.f, 0.f, 0.f, 0.f};
#pragma unroll
    for (int m = 0; m < 4; m++)
#pragma unroll
        for (int nt = 0; nt < 7; nt++) acc[m][nt] = zz;
#pragma unroll
    for (int nt = 0; nt < 7; nt++) {
        size_t brow = ((size_t)(b * HW + p0 + nt * 16 + ln)) * 64;
#pragma unroll
        for (int ks = 0; ks < 2; ks++) {
            short8 bfr = *(const short8*)(out2h + brow + ks * 32 + g * 8);
#pragma unroll
            for (int m = 0; m < 4; m++) acc[m][nt] = MFMA16(afr[m][ks], bfr, acc[m][nt]);
        }
    }
#pragma unroll
    for (int nt = 0; nt < 7; nt++) {
        int p = p0 + nt * 16 + ln;
        float mv = mask[b * HW + p];
#pragma unroll
        for (int m = 0; m < 4; m++) {
#pragma unroll
            for (int i = 0; i < 4; i++) {
                int oc = w * 64 + m * 16 + g * 4 + i;
                size_t idx = ((size_t)(b * COUT + oc)) * HW + p;
                float y = (acc[m][nt][i] * sc[oc] + sh[oc]) * mv;
                out[idx] = fmaxf(x[idx] + y, 0.f);
            }
        }
    }
}

extern "C" void kernel_launch(void* const* d_in, const int* in_sizes, int n_in,
                              void* d_out, int out_size, void* d_ws, size_t ws_size,
                              hipStream_t stream) {
    const float* x       = (const float*)d_in[0];
    const float* conv1_w = (const float*)d_in[1];
    const float* bn1_g   = (const float*)d_in[2];
    const float* bn1_b   = (const float*)d_in[3];
    const float* bn1_m   = (const float*)d_in[4];
    const float* bn1_v   = (const float*)d_in[5];
    const float* conv2_w = (const float*)d_in[6];
    const float* bn2_g   = (const float*)d_in[7];
    const float* bn2_b   = (const float*)d_in[8];
    const float* bn2_m   = (const float*)d_in[9];
    const float* bn2_v   = (const float*)d_in[10];
    const float* conv3_w = (const float*)d_in[11];
    const float* bn3_g   = (const float*)d_in[12];
    const float* bn3_b   = (const float*)d_in[13];
    const float* bn3_m   = (const float*)d_in[14];
    const float* bn3_v   = (const float*)d_in[15];
    const float* fc_w    = (const float*)d_in[16];
    const float* fc_b    = (const float*)d_in[17];
    const float* mask_w  = (const float*)d_in[18];
    const float* mask_b  = (const float*)d_in[19];

    char* wsb = (char*)d_ws;
    size_t off = 0;
    double* pooled = (double*)(wsb + off); off += (size_t)BATCH * CIN * 8;        // 128 KB
    double* spsal  = (double*)(wsb + off); off += (size_t)BATCH * HW * 8;         // 1.6 MB
    float* vector  = (float*)(wsb + off);  off += (size_t)BATCH * WIDTH * 4;
    float* mask    = (float*)(wsb + off);  off += (size_t)BATCH * HW * 4;
    float* mdil    = (float*)(wsb + off);  off += (size_t)BATCH * HW * 4;
    short* w1bf    = (short*)(wsb + off);  off += (size_t)WIDTH * CIN * 2;        // 32 KB
    short* wt2     = (short*)(wsb + off);  off += (size_t)9 * WIDTH * WIDTH * 2;  // 72 KB
    short* w3bf    = (short*)(wsb + off);  off += (size_t)COUT * WIDTH * 2;       // 32 KB
    short* out1h   = (short*)(wsb + off);  off += (size_t)BATCH * HW * WIDTH * 2; // 25.7 MB (NHWC)
    short* out2h   = (short*)(wsb + off);  off += (size_t)BATCH * HW * WIDTH * 2; // 25.7 MB (NHWC)
    (void)ws_size; (void)in_sizes; (void)n_in; (void)out_size;

    k_prep<<<272, 256, 0, stream>>>(conv1_w, conv2_w, conv3_w, w1bf, wt2, w3bf);
    k_pool<<<BATCH * CIN, 256, 0, stream>>>(x, pooled);
    k_spsal<<<(BATCH * HW + 255) / 256, 256, 0, stream>>>(x, mask_w, mask_b, spsal);
    k_chan<<<BATCH, 64, 0, stream>>>(pooled, fc_w, fc_b, vector);
    k_spmask<<<BATCH, 1024, 0, stream>>>(spsal, mask, mdil);
    k_conv1<<<dim3(7, BATCH), 256, 0, stream>>>(x, w1bf, bn1_g, bn1_b, bn1_m, bn1_v, mdil, vector, out1h);
    k_conv2<<<dim3(7, BATCH), 256, 0, stream>>>(out1h, wt2, bn2_g, bn2_b, bn2_m, bn2_v, mask, vector, out2h);
    k_conv3<<<dim3(28, BATCH), 256, 0, stream>>>(out2h, w3bf, bn3_g, bn3_b, bn3_m, bn3_v, mask, x, (float*)d_out);
}

// Round 3
// 403.671 us; speedup vs baseline: 2.7169x; 1.3221x over previous
//
#include <hip/hip_runtime.h>
#include <math.h>

#define BATCH 64
#define CIN   256
#define HH    56
#define WW    56
#define HW    (HH*WW)      // 3136
#define WIDTH 64
#define COUT  256
#define K_CH  32
#define K_SP  1568
#define EPS   1e-5f

typedef short short8 __attribute__((ext_vector_type(8)));
typedef float f32x4 __attribute__((ext_vector_type(4)));

#define MFMA16(a, b, c) __builtin_amdgcn_mfma_f32_16x16x32_bf16((a), (b), (c), 0, 0, 0)

__device__ __forceinline__ unsigned short f2bf(float f) {
    unsigned u = __builtin_bit_cast(unsigned, f);
    u += 0x7fffu + ((u >> 16) & 1u);
    return (unsigned short)(u >> 16);
}

// ---------------- Kernel 0: weight prep (fp32 -> bf16, conv2 -> [tap][oc][c]) ----------------
__global__ __launch_bounds__(256) void k_prep(const float* __restrict__ w1,
                                              const float* __restrict__ w2,
                                              const float* __restrict__ w3,
                                              short* __restrict__ w1bf,
                                              short* __restrict__ wt2,
                                              short* __restrict__ w3bf) {
    int i = blockIdx.x * 256 + threadIdx.x;
    if (i < 16384) {
        w1bf[i] = (short)f2bf(w1[i]);
    } else if (i < 53248) {
        int j = i - 16384;              // [tap][oc][c]
        int tap = j >> 12, rem = j & 4095;
        int oc = rem >> 6, c = rem & 63;
        wt2[j] = (short)f2bf(w2[oc * 576 + c * 9 + tap]);
    } else if (i < 69632) {
        int j = i - 53248;
        w3bf[j] = (short)f2bf(w3[j]);
    }
}

// ---------------- Kernel 1: global average pool (double) ----------------
__global__ __launch_bounds__(256) void k_pool(const float* __restrict__ x, double* __restrict__ pooled) {
    int bc = blockIdx.x;
    const float* px = x + (size_t)bc * HW;
    double s = 0.0;
    for (int i = threadIdx.x; i < HW; i += 256) s += (double)px[i];
    __shared__ double red[256];
    red[threadIdx.x] = s;
    __syncthreads();
    for (int off = 128; off > 0; off >>= 1) {
        if (threadIdx.x < off) red[threadIdx.x] += red[threadIdx.x + off];
        __syncthreads();
    }
    if (threadIdx.x == 0) pooled[bc] = red[0] * (1.0 / (double)HW);
}

// ---------------- Kernel 2: spatial saliency 1x1 conv (double accum) ----------------
__global__ __launch_bounds__(256) void k_spsal(const float* __restrict__ x,
                                               const float* __restrict__ mask_w,
                                               const float* __restrict__ mask_b,
                                               double* __restrict__ spsal) {
    __shared__ float wsh[CIN];
    for (int i = threadIdx.x; i < CIN; i += 256) wsh[i] = mask_w[i];
    __syncthreads();
    int g = blockIdx.x * 256 + threadIdx.x;
    if (g >= BATCH * HW) return;
    int b = g / HW, p = g % HW;
    const float* px = x + (size_t)b * CIN * HW + p;
    double acc = 0.0;
#pragma unroll 8
    for (int c = 0; c < CIN; c++) acc += (double)px[(size_t)c * HW] * (double)wsh[c];
    spsal[g] = acc + (double)mask_b[0];
}

// ---------------- Kernel 3: channel saliency + top-K_CH mask ----------------
__global__ __launch_bounds__(64) void k_chan(const double* __restrict__ pooled,
                                             const float* __restrict__ fc_w,
                                             const float* __restrict__ fc_b,
                                             float* __restrict__ vector) {
    int b = blockIdx.x;
    int j = threadIdx.x;
    __shared__ double ps[CIN];
    for (int i = j; i < CIN; i += 64) ps[i] = pooled[b * CIN + i];
    __syncthreads();
    double acc = (double)fc_b[j];
    const float* wr = fc_w + j * CIN;
    for (int k = 0; k < CIN; k++) acc += ps[k] * (double)wr[k];
    double sal = 1.0 / (1.0 + exp(-acc));
    __shared__ double ss[WIDTH];
    __shared__ double kth;
    ss[j] = sal;
    __syncthreads();
    int cg = 0, ce = 0;
    for (int i = 0; i < WIDTH; i++) {
        cg += (ss[i] > sal);
        ce += (ss[i] == sal);
    }
    if (cg <= K_CH - 1 && cg + ce >= K_CH) kth = sal;
    __syncthreads();
    vector[b * WIDTH + j] = (sal >= kth) ? 1.0f : 0.0f;
}

// ---------------- Kernel 4: spatial kth (bitonic select) + mask + 3x3 dilate ----------------
__global__ __launch_bounds__(1024) void k_spmask(const double* __restrict__ spsal,
                                                 float* __restrict__ mask,
                                                 float* __restrict__ mdil) {
    int b = blockIdx.x;
    int tid = threadIdx.x;
    __shared__ double s[4096];
    __shared__ float m[HW];
    for (int i = tid; i < 4096; i += 1024)
        s[i] = (i < HW) ? spsal[b * HW + i] : 1e300;
    __syncthreads();
    for (int k2 = 2; k2 <= 4096; k2 <<= 1) {
        for (int j2 = k2 >> 1; j2 > 0; j2 >>= 1) {
            for (int i = tid; i < 4096; i += 1024) {
                int ixj = i ^ j2;
                if (ixj > i) {
                    double a = s[i], c = s[ixj];
                    bool asc = ((i & k2) == 0);
                    bool swap = asc ? (a > c) : (a < c);
                    if (swap) { s[i] = c; s[ixj] = a; }
                }
            }
            __syncthreads();
        }
    }
    double kth = s[HW - K_SP];
    __syncthreads();
    for (int p = tid; p < HW; p += 1024) {
        float mv = (spsal[b * HW + p] >= kth) ? 1.0f : 0.0f;
        m[p] = mv;
        mask[b * HW + p] = mv;
    }
    __syncthreads();
    for (int p = tid; p < HW; p += 1024) {
        int y = p / WW, xx = p % WW;
        float mx = 0.0f;
        for (int dy = -1; dy <= 1; dy++) {
            int yy = y + dy;
            if (yy < 0 || yy >= HH) continue;
            for (int dx = -1; dx <= 1; dx++) {
                int xc = xx + dx;
                if (xc < 0 || xc >= WW) continue;
                mx = fmaxf(mx, m[yy * WW + xc]);
            }
        }
        mdil[b * HW + p] = mx;
    }
}

// ---------------- Kernel 5: conv1 1x1 (256->64) MFMA + bn1 + relu + mdil + vector -> NHWC bf16 ----------------
__global__ __launch_bounds__(256, 2) void k_conv1(const float* __restrict__ x,
                                                  const short* __restrict__ w1bf,
                                                  const float* __restrict__ g1, const float* __restrict__ b1,
                                                  const float* __restrict__ m1, const float* __restrict__ v1,
                                                  const float* __restrict__ mdil,
                                                  const float* __restrict__ vec,
                                                  short* __restrict__ out1h) {
    __shared__ short lds[448 * 64];   // [px][c^swz], 57344 B
    __shared__ float sc[64], sh[64], vs[64];
    int b = blockIdx.y, r0 = blockIdx.x * 8, p0 = r0 * 56;
    int tid = threadIdx.x, w = tid >> 6, lane = tid & 63, g = lane >> 4, ln = lane & 15;
    if (tid < 64) {
        float s = g1[tid] * rsqrtf(v1[tid] + EPS);
        sc[tid] = s; sh[tid] = b1[tid] - m1[tid] * s;
        vs[tid] = vec[b * 64 + tid];
    }
    f32x4 acc[4][7];
    f32x4 zz = {0.f, 0.f, 0.f, 0.f};
#pragma unroll
    for (int m = 0; m < 4; m++)
#pragma unroll
        for (int nt = 0; nt < 7; nt++) acc[m][nt] = zz;

    int pxl0 = w * 112 + ln;
    int swl = (pxl0 & 7) << 3;

    for (int kc = 0; kc < 4; kc++) {
        __syncthreads();
        const float* xsrc = x + ((size_t)(b * 256 + kc * 64)) * HW + p0;
        {
            int c = 0, px = tid;
            for (int i = 0; i < 112; i++) {
                float f = xsrc[(size_t)c * HW + px];
                lds[px * 64 + (c ^ ((px & 7) << 3))] = (short)f2bf(f);
                px += 256;
                if (px >= 448) { px -= 448; c++; }
            }
        }
        __syncthreads();
        short8 afr[4][2];
#pragma unroll
        for (int m = 0; m < 4; m++)
#pragma unroll
            for (int ks = 0; ks < 2; ks++)
                afr[m][ks] = *(const short8*)(w1bf + ((m * 16 + ln) * 256 + kc * 64 + ks * 32 + g * 8));
#pragma unroll
        for (int nt = 0; nt < 7; nt++) {
#pragma unroll
            for (int ks = 0; ks < 2; ks++) {
                short8 bfr = *(const short8*)(&lds[(pxl0 + nt * 16) * 64 + (((ks * 32 + g * 8)) ^ swl)]);
#pragma unroll
                for (int m = 0; m < 4; m++) acc[m][nt] = MFMA16(afr[m][ks], bfr, acc[m][nt]);
            }
        }
    }
#pragma unroll
    for (int nt = 0; nt < 7; nt++) {
        int px = p0 + pxl0 + nt * 16;
        float md = mdil[b * HW + px];
#pragma unroll
        for (int m = 0; m < 4; m++) {
            unsigned pk0, pk1;
            {
                int oc = m * 16 + g * 4;
                float y0 = fmaxf(acc[m][nt][0] * sc[oc + 0] + sh[oc + 0], 0.f) * md * vs[oc + 0];
                float y1 = fmaxf(acc[m][nt][1] * sc[oc + 1] + sh[oc + 1], 0.f) * md * vs[oc + 1];
                float y2 = fmaxf(acc[m][nt][2] * sc[oc + 2] + sh[oc + 2], 0.f) * md * vs[oc + 2];
                float y3 = fmaxf(acc[m][nt][3] * sc[oc + 3] + sh[oc + 3], 0.f) * md * vs[oc + 3];
                pk0 = (unsigned)f2bf(y0) | ((unsigned)f2bf(y1) << 16);
                pk1 = (unsigned)f2bf(y2) | ((unsigned)f2bf(y3) << 16);
            }
            uint2 u; u.x = pk0; u.y = pk1;
            *(uint2*)(out1h + ((size_t)(b * HW + px)) * 64 + m * 16 + g * 4) = u;
        }
    }
}

// ---------------- Kernel 6: conv2 3x3 (64->64) MFMA shift-GEMM + bn2 + relu + mask + vector ----------------
__global__ __launch_bounds__(256, 2) void k_conv2(const short* __restrict__ out1h,
                                                  const short* __restrict__ wt2,
                                                  const float* __restrict__ g2, const float* __restrict__ b2,
                                                  const float* __restrict__ m2, const float* __restrict__ v2,
                                                  const float* __restrict__ mask,
                                                  const float* __restrict__ vec,
                                                  short* __restrict__ out2h) {
    __shared__ short lds[10 * 58 * 64];   // 74240 B
    __shared__ float sc[64], sh[64], vs[64];
    int b = blockIdx.y, r0 = blockIdx.x * 8, p0 = r0 * 56;
    int tid = threadIdx.x, w = tid >> 6, lane = tid & 63, g = lane >> 4, ln = lane & 15;
    if (tid < 64) {
        float s = g2[tid] * rsqrtf(v2[tid] + EPS);
        sc[tid] = s; sh[tid] = b2[tid] - m2[tid] * s;
        vs[tid] = vec[b * 64 + tid];
    }
    short8 z8 = {0, 0, 0, 0, 0, 0, 0, 0};
    for (int i = tid; i < 4640; i += 256) {
        int ri = i / 464, rem = i - ri * 464;
        int col = rem >> 3, c8 = (rem & 7) << 3;
        int gr = r0 - 1 + ri, gc = col - 1;
        short8 v8 = z8;
        if (gr >= 0 && gr < HH && gc >= 0 && gc < WW)
            v8 = *(const short8*)(out1h + ((size_t)(b * HW + gr * WW + gc)) * 64 + c8);
        *(short8*)(&lds[(ri * 58 + col) * 64 + (c8 ^ ((col & 7) << 3))]) = v8;
    }
    __syncthreads();

    f32x4 acc[4][7];
    f32x4 zz = {0.f, 0.f, 0.f, 0.f};
#pragma unroll
    for (int m = 0; m < 4; m++)
#pragma unroll
        for (int nt = 0; nt < 7; nt++) acc[m][nt] = zz;

    int prel0 = w * 112 + ln;
    for (int tap = 0; tap < 9; tap++) {
        int dy = tap / 3 - 1;
        int dx = tap - (tap / 3) * 3 - 1;
        short8 afr[4][2];
        const short* wt = wt2 + tap * 4096;
#pragma unroll
        for (int m = 0; m < 4; m++)
#pragma unroll
            for (int ks = 0; ks < 2; ks++)
                afr[m][ks] = *(const short8*)(wt + (m * 16 + ln) * 64 + ks * 32 + g * 8);
#pragma unroll
        for (int nt = 0; nt < 7; nt++) {
            int prel = prel0 + nt * 16;
            int rrel = prel / 56;
            int xcol = prel - rrel * 56;
            int row_l = rrel + 1 + dy;
            int col_l = xcol + 1 + dx;
            int base = (row_l * 58 + col_l) * 64;
            int sw = (col_l & 7) << 3;
#pragma unroll
            for (int ks = 0; ks < 2; ks++) {
                short8 bfr = *(const short8*)(&lds[base + ((ks * 32 + g * 8) ^ sw)]);
#pragma unroll
                for (int m = 0; m < 4; m++) acc[m][nt] = MFMA16(afr[m][ks], bfr, acc[m][nt]);
            }
        }
    }
#pragma unroll
    for (int nt = 0; nt < 7; nt++) {
        int px = p0 + prel0 + nt * 16;
        float mv = mask[b * HW + px];
#pragma unroll
        for (int m = 0; m < 4; m++) {
            int oc = m * 16 + g * 4;
            float y0 = fmaxf(acc[m][nt][0] * sc[oc + 0] + sh[oc + 0], 0.f) * mv * vs[oc + 0];
            float y1 = fmaxf(acc[m][nt][1] * sc[oc + 1] + sh[oc + 1], 0.f) * mv * vs[oc + 1];
            float y2 = fmaxf(acc[m][nt][2] * sc[oc + 2] + sh[oc + 2], 0.f) * mv * vs[oc + 2];
            float y3 = fmaxf(acc[m][nt][3] * sc[oc + 3] + sh[oc + 3], 0.f) * mv * vs[oc + 3];
            uint2 u;
            u.x = (unsigned)f2bf(y0) | ((unsigned)f2bf(y1) << 16);
            u.y = (unsigned)f2bf(y2) | ((unsigned)f2bf(y3) << 16);
            *(uint2*)(out2h + ((size_t)(b * HW + px)) * 64 + m * 16 + g * 4) = u;
        }
    }
}

// ---------------- Kernel 7: conv3 1x1 (64->256) MFMA (SWAPPED operands) + bn3 + mask + residual + relu ----------------
// grid (56, BATCH): blockIdx.x = ocb*28 + pxb; 256 thr = 4 waves; wave: 32 oc x 112 px.
// Swapped MFMA(A=act, B=weight) -> lane holds 4 CONSECUTIVE PIXELS per reg -> float4 x/mask/out.
__global__ __launch_bounds__(256, 2) void k_conv3(const short* __restrict__ out2h,
                                                  const short* __restrict__ w3bf,
                                                  const float* __restrict__ g3, const float* __restrict__ b3,
                                                  const float* __restrict__ m3, const float* __restrict__ v3,
                                                  const float* __restrict__ mask,
                                                  const float* __restrict__ x,
                                                  float* __restrict__ out) {
    __shared__ float sc[COUT], sh[COUT];
    int b = blockIdx.y;
    int ocb = blockIdx.x / 28;          // 0..1
    int pxb = blockIdx.x % 28;          // 0..27
    int p0 = pxb * 112;
    int tid = threadIdx.x, w = tid >> 6, lane = tid & 63, g = lane >> 4, ln = lane & 15;
    {
        float s = g3[tid] * rsqrtf(v3[tid] + EPS);
        sc[tid] = s; sh[tid] = b3[tid] - m3[tid] * s;
    }
    __syncthreads();
    int oc0 = ocb * 128 + w * 32;
    short8 wfr[2][2];
#pragma unroll
    for (int m = 0; m < 2; m++)
#pragma unroll
        for (int ks = 0; ks < 2; ks++)
            wfr[m][ks] = *(const short8*)(w3bf + ((oc0 + m * 16 + ln) * 64 + ks * 32 + g * 8));
    f32x4 acc[2][7];
    f32x4 zz = {0.f, 0.f, 0.f, 0.f};
#pragma unroll
    for (int m = 0; m < 2; m++)
#pragma unroll
        for (int nt = 0; nt < 7; nt++) acc[m][nt] = zz;
#pragma unroll
    for (int nt = 0; nt < 7; nt++) {
        size_t arow = ((size_t)(b * HW + p0 + nt * 16 + ln)) * 64;
#pragma unroll
        for (int ks = 0; ks < 2; ks++) {
            short8 act = *(const short8*)(out2h + arow + ks * 32 + g * 8);
#pragma unroll
            for (int m = 0; m < 2; m++) acc[m][nt] = MFMA16(act, wfr[m][ks], acc[m][nt]);
        }
    }
    // epilogue: lane holds px = p0 + nt*16 + g*4 + i, oc = oc0 + m*16 + ln -> float4 along px
#pragma unroll
    for (int nt = 0; nt < 7; nt++) {
        int px0 = p0 + nt * 16 + g * 4;
        f32x4 mv = *(const f32x4*)(mask + (size_t)b * HW + px0);
#pragma unroll
        for (int m = 0; m < 2; m++) {
            int oc = oc0 + m * 16 + ln;
            float s = sc[oc], h = sh[oc];
            size_t idx = ((size_t)(b * COUT + oc)) * HW + px0;
            f32x4 xr = *(const f32x4*)(x + idx);
            f32x4 o;
#pragma unroll
            for (int i = 0; i < 4; i++)
                o[i] = fmaxf(xr[i] + (acc[m][nt][i] * s + h) * mv[i], 0.f);
            *(f32x4*)(out + idx) = o;
        }
    }
}

extern "C" void kernel_launch(void* const* d_in, const int* in_sizes, int n_in,
                              void* d_out, int out_size, void* d_ws, size_t ws_size,
                              hipStream_t stream) {
    const float* x       = (const float*)d_in[0];
    const float* conv1_w = (const float*)d_in[1];
    const float* bn1_g   = (const float*)d_in[2];
    const float* bn1_b   = (const float*)d_in[3];
    const float* bn1_m   = (const float*)d_in[4];
    const float* bn1_v   = (const float*)d_in[5];
    const float* conv2_w = (const float*)d_in[6];
    const float* bn2_g   = (const float*)d_in[7];
    const float* bn2_b   = (const float*)d_in[8];
    const float* bn2_m   = (const float*)d_in[9];
    const float* bn2_v   = (const float*)d_in[10];
    const float* conv3_w = (const float*)d_in[11];
    const float* bn3_g   = (const float*)d_in[12];
    const float* bn3_b   = (const float*)d_in[13];
    const float* bn3_m   = (const float*)d_in[14];
    const float* bn3_v   = (const float*)d_in[15];
    const float* fc_w    = (const float*)d_in[16];
    const float* fc_b    = (const float*)d_in[17];
    const float* mask_w  = (const float*)d_in[18];
    const float* mask_b  = (const float*)d_in[19];

    char* wsb = (char*)d_ws;
    size_t off = 0;
    double* pooled = (double*)(wsb + off); off += (size_t)BATCH * CIN * 8;
    double* spsal  = (double*)(wsb + off); off += (size_t)BATCH * HW * 8;
    float* vector  = (float*)(wsb + off);  off += (size_t)BATCH * WIDTH * 4;
    float* mask    = (float*)(wsb + off);  off += (size_t)BATCH * HW * 4;
    float* mdil    = (float*)(wsb + off);  off += (size_t)BATCH * HW * 4;
    short* w1bf    = (short*)(wsb + off);  off += (size_t)WIDTH * CIN * 2;
    short* wt2     = (short*)(wsb + off);  off += (size_t)9 * WIDTH * WIDTH * 2;
    short* w3bf    = (short*)(wsb + off);  off += (size_t)COUT * WIDTH * 2;
    short* out1h   = (short*)(wsb + off);  off += (size_t)BATCH * HW * WIDTH * 2;
    short* out2h   = (short*)(wsb + off);  off += (size_t)BATCH * HW * WIDTH * 2;
    (void)ws_size; (void)in_sizes; (void)n_in; (void)out_size;

    k_prep<<<272, 256, 0, stream>>>(conv1_w, conv2_w, conv3_w, w1bf, wt2, w3bf);
    k_pool<<<BATCH * CIN, 256, 0, stream>>>(x, pooled);
    k_spsal<<<(BATCH * HW + 255) / 256, 256, 0, stream>>>(x, mask_w, mask_b, spsal);
    k_chan<<<BATCH, 64, 0, stream>>>(pooled, fc_w, fc_b, vector);
    k_spmask<<<BATCH, 1024, 0, stream>>>(spsal, mask, mdil);
    k_conv1<<<dim3(7, BATCH), 256, 0, stream>>>(x, w1bf, bn1_g, bn1_b, bn1_m, bn1_v, mdil, vector, out1h);
    k_conv2<<<dim3(7, BATCH), 256, 0, stream>>>(out1h, wt2, bn2_g, bn2_b, bn2_m, bn2_v, mask, vector, out2h);
    k_conv3<<<dim3(56, BATCH), 256, 0, stream>>>(out2h, w3bf, bn3_g, bn3_b, bn3_m, bn3_v, mask, x, (float*)d_out);
}